// Round 8
// baseline (35.768 us; speedup 1.0000x reference)
//
#include <hip/hip_runtime.h>

using short8 = __attribute__((ext_vector_type(8))) short;
using f32x4  = __attribute__((ext_vector_type(4))) float;

constexpr int D       = 64;
constexpr int K       = 1024;
constexpr int NROWS   = 32768;
constexpr int THREADS = 512;           // 8 waves: 4 row-groups x 2 code-halves
constexpr int RPB     = 128;           // rows per block
constexpr int NBLK    = NROWS / RPB;   // 256 = one block per CU

__device__ __forceinline__ unsigned short f2bf(float f) {
    unsigned u = __builtin_bit_cast(unsigned, f);
    u = (u + 0x7FFFu + ((u >> 16) & 1u)) >> 16;   // RNE
    return (unsigned short)u;
}

__device__ __forceinline__ short8 pack8(float4 v0, float4 v1) {
    short8 pk;
    pk[0] = (short)f2bf(v0.x); pk[1] = (short)f2bf(v0.y);
    pk[2] = (short)f2bf(v0.z); pk[3] = (short)f2bf(v0.w);
    pk[4] = (short)f2bf(v1.x); pk[5] = (short)f2bf(v1.y);
    pk[6] = (short)f2bf(v1.z); pk[7] = (short)f2bf(v1.w);
    return pk;
}

// truncating bf16x2 pack: low short = first arg, high short = second
__device__ __forceinline__ unsigned pk2(float f0, float f1) {
    return __builtin_amdgcn_perm(__builtin_bit_cast(unsigned, f1),
                                 __builtin_bit_cast(unsigned, f0), 0x07060302u);
}
__device__ __forceinline__ float bflo(unsigned u) { return __builtin_bit_cast(float, u << 16); }
__device__ __forceinline__ float bfhi(unsigned u) { return __builtin_bit_cast(float, u & 0xFFFF0000u); }

__global__ __launch_bounds__(THREADS, 2) void vq_main(
    const float* __restrict__ x, const float* __restrict__ cb,
    float* __restrict__ qst, double* __restrict__ mse_acc, int* __restrict__ counts) {

    __shared__ unsigned short s_cb[K * D];     // 128 KB bf16, XOR-swizzled, whole codebook
    __shared__ float s_sc[RPB][2];
    __shared__ int   s_sk[RPB][2];
    __shared__ int   s_kwin[RPB];
    __shared__ float s_red[8];

    const int tid  = threadIdx.x;
    const int lane = tid & 63;
    const int w    = __builtin_amdgcn_readfirstlane(tid >> 6);  // 0..7
    const int h    = w & 1;           // code half: [h*512, +512)
    const int rg   = w >> 1;          // row-group 0..3 (32 rows each)
    const int mrow = lane & 15;
    const int kgrp = lane >> 4;
    const int bbase = blockIdx.x * RPB;
    const int wbase = bbase + rg * 32;

    // resident B-frags: rows wbase+mrow and wbase+16+mrow (RNE, 16 VGPRs)
    short8 b00, b01, b10, b11;
    {
        const float* p0 = x + (size_t)(wbase + mrow) * D + kgrp * 8;
        b00 = pack8(*(const float4*)(p0),      *(const float4*)(p0 + 4));
        b01 = pack8(*(const float4*)(p0 + 32), *(const float4*)(p0 + 36));
        const float* p1 = p0 + (size_t)16 * D;
        b10 = pack8(*(const float4*)(p1),      *(const float4*)(p1 + 4));
        b11 = pack8(*(const float4*)(p1 + 32), *(const float4*)(p1 + 36));
    }

    // stage entire codebook: two batches of 8 in-flight load-pairs (deep pipeline)
    {
        const int g  = tid & 7;
        const int c0 = tid >> 3;                       // 0..63
        const unsigned swz = (unsigned)((c0 & 7) << 4); // (code&7)==(c0&7): 64*i keeps low bits
#pragma unroll
        for (int b = 0; b < 2; ++b) {
            float4 va[8], vb[8];
#pragma unroll
            for (int i = 0; i < 8; ++i) {              // issue all 16 loads first
                const float* p = cb + (size_t)(c0 + 64 * (b * 8 + i)) * D + g * 8;
                va[i] = *(const float4*)(p);
                vb[i] = *(const float4*)(p + 4);
            }
#pragma unroll
            for (int i = 0; i < 8; ++i) {              // pack + write as they land
                const int code = c0 + 64 * (b * 8 + i);
                uint4 pk = { pk2(va[i].x, va[i].y), pk2(va[i].z, va[i].w),
                             pk2(vb[i].x, vb[i].y), pk2(vb[i].z, vb[i].w) };
                *(uint4*)((char*)s_cb + (((unsigned)(code * 128 + g * 16)) ^ swz)) = pk;
            }
        }
    }
    __syncthreads();

    // scan this wave's half: 32 subtiles, one A-read feeds 2 row-group chains
    float bs0[4], bs1[4]; int bk0[4], bk1[4];
#pragma unroll
    for (int r = 0; r < 4; ++r) { bs0[r] = -3.4e38f; bk0[r] = 0; bs1[r] = -3.4e38f; bk1[r] = 0; }

    const char* base = (const char*)s_cb + h * 512 * 128;   // this half's bytes
    const unsigned aswz = (unsigned)((mrow & 7) << 4);

#pragma unroll
    for (int t = 0; t < 32; ++t) {
        const int ci = t * 16 + mrow;                        // code within half
        unsigned ab = ((unsigned)(ci * 128 + kgrp * 16)) ^ aswz;
        short8 a0 = *(const short8*)(base + ab);
        short8 a1 = *(const short8*)(base + (ab ^ 64u));
        f32x4 z = {0.f, 0.f, 0.f, 0.f};
        f32x4 acc0 = __builtin_amdgcn_mfma_f32_16x16x32_bf16(a0, b00, z, 0, 0, 0);
        acc0       = __builtin_amdgcn_mfma_f32_16x16x32_bf16(a1, b01, acc0, 0, 0, 0);
        f32x4 acc1 = __builtin_amdgcn_mfma_f32_16x16x32_bf16(a0, b10, z, 0, 0, 0);
        acc1       = __builtin_amdgcn_mfma_f32_16x16x32_bf16(a1, b11, acc1, 0, 0, 0);
        const int kb = h * 512 + t * 16 + kgrp * 4;
#pragma unroll
        for (int r = 0; r < 4; ++r) {        // k ascending per chain: '>' keeps smallest k
            if (acc0[r] > bs0[r]) { bs0[r] = acc0[r]; bk0[r] = kb + r; }
            if (acc1[r] > bs1[r]) { bs1[r] = acc1[r]; bk1[r] = kb + r; }
        }
    }

    // merge 4 chains per row-group (exact, smallest-k tie-break)
    float f0 = bs0[0]; int k0 = bk0[0];
    float f1 = bs1[0]; int k1 = bk1[0];
#pragma unroll
    for (int r = 1; r < 4; ++r) {
        if (bs0[r] > f0 || (bs0[r] == f0 && bk0[r] < k0)) { f0 = bs0[r]; k0 = bk0[r]; }
        if (bs1[r] > f1 || (bs1[r] == f1 && bk1[r] < k1)) { f1 = bs1[r]; k1 = bk1[r]; }
    }
    // combine the 4 kgrp copies of each x-row
#pragma unroll
    for (int off = 16; off <= 32; off <<= 1) {
        float o0 = __shfl_xor(f0, off); int q0 = __shfl_xor(k0, off);
        float o1 = __shfl_xor(f1, off); int q1 = __shfl_xor(k1, off);
        if (o0 > f0 || (o0 == f0 && q0 < k0)) { f0 = o0; k0 = q0; }
        if (o1 > f1 || (o1 == f1 && q1 < k1)) { f1 = o1; k1 = q1; }
    }
    if (lane < 16) {
        s_sc[rg * 32 + lane][h]      = f0;  s_sk[rg * 32 + lane][h]      = k0;
        s_sc[rg * 32 + 16 + lane][h] = f1;  s_sk[rg * 32 + 16 + lane][h] = k1;
    }
    __syncthreads();

    // cross-half merge (h=0 codes < h=1 codes: tie -> h=0 keeps smaller k)
    if (tid < RPB) {
        float sA = s_sc[tid][0]; int kA = s_sk[tid][0];
        float sB = s_sc[tid][1]; int kB = s_sk[tid][1];
        int kwin = (sB > sA) ? kB : kA;
        s_kwin[tid] = kwin;
        atomicAdd(&counts[kwin], 1);          // direct global histogram (low contention)
    }
    __syncthreads();

    // epilogue: 4 threads per row x 16 dims; codes read from LDS (bf16)
    float mse = 0.f;
    {
        const int r  = tid >> 2;               // 0..127
        const int d0 = (tid & 3) * 16;
        const int k  = s_kwin[r];
        const int grow = bbase + r;
        const float* xr = x   + (size_t)grow * D + d0;
        float*       qr = qst + (size_t)grow * D + d0;
        const unsigned sw  = (unsigned)((k & 7) << 4);
        const unsigned byt = (unsigned)(k * 128 + d0 * 2);
        uint4 e0 = *(const uint4*)((const char*)s_cb + (byt ^ sw));
        uint4 e1 = *(const uint4*)((const char*)s_cb + ((byt + 16u) ^ sw));
        unsigned ew[8] = { e0.x, e0.y, e0.z, e0.w, e1.x, e1.y, e1.z, e1.w };
        const float4* xp4 = (const float4*)xr;
        float4*       qp4 = (float4*)qr;
#pragma unroll
        for (int i = 0; i < 4; ++i) {
            float4 xv = xp4[i];
            float ex = bflo(ew[2 * i]),     ey = bfhi(ew[2 * i]);
            float ez = bflo(ew[2 * i + 1]), ec = bfhi(ew[2 * i + 1]);
            float dx = ex - xv.x, dy = ey - xv.y, dz = ez - xv.z, dw = ec - xv.w;
            qp4[i] = make_float4(xv.x + dx, xv.y + dy, xv.z + dz, xv.w + dw);
            mse = fmaf(dx, dx, mse); mse = fmaf(dy, dy, mse);
            mse = fmaf(dz, dz, mse); mse = fmaf(dw, dw, mse);
        }
    }

    // block mse reduce -> one double atomic
#pragma unroll
    for (int off = 32; off; off >>= 1) mse += __shfl_xor(mse, off);
    if (lane == 0) s_red[w] = mse;
    __syncthreads();
    if (tid == 0) {
        float m = 0.f;
#pragma unroll
        for (int i = 0; i < 8; ++i) m += s_red[i];
        atomicAdd(mse_acc, (double)m);
    }
}

// ---- finalize: loss + perplexity (kernel boundary = coherence point) ----
__global__ void vq_final(const int* __restrict__ counts,
                         const double* __restrict__ mse_acc,
                         float* __restrict__ out_loss,
                         float* __restrict__ out_ppl) {
    __shared__ float wsum[16];
    const int t = threadIdx.x;  // 1024 threads
    float p = (float)counts[t] * (1.0f / (float)NROWS);
    float term = p * logf(p + 1e-10f);
#pragma unroll
    for (int off = 32; off; off >>= 1) term += __shfl_xor(term, off);
    if ((t & 63) == 0) wsum[t >> 6] = term;
    __syncthreads();
    if (t == 0) {
        float s = 0.f;
#pragma unroll
        for (int i = 0; i < 16; ++i) s += wsum[i];
        *out_ppl  = expf(-s);
        *out_loss = (float)(1.25 * (*mse_acc) * (1.0 / ((double)NROWS * D)));
    }
}

extern "C" void kernel_launch(void* const* d_in, const int* in_sizes, int n_in,
                              void* d_out, int out_size, void* d_ws, size_t ws_size,
                              hipStream_t stream) {
    const float* x  = (const float*)d_in[0];   // (32768, 64)
    const float* cb = (const float*)d_in[1];   // (1024, 64)
    float* out = (float*)d_out;                // [qst | loss | ppl]

    char* ws = (char*)d_ws;
    int*    counts = (int*)   (ws);            // 4096 B
    double* mse    = (double*)(ws + 4096);     // 8 B

    hipMemsetAsync(ws, 0, 4104, stream);

    vq_main <<<NBLK, THREADS, 0, stream>>>(x, cb, out, mse, counts);
    vq_final<<<1, 1024, 0, stream>>>(counts, mse,
                                     out + (size_t)out_size - 2,
                                     out + (size_t)out_size - 1);
}